// Round 13
// baseline (130.954 us; speedup 1.0000x reference)
//
#include <hip/hip_runtime.h>

typedef unsigned short u16;
typedef unsigned int u32;
typedef __attribute__((ext_vector_type(4))) unsigned short u16x4;
typedef __attribute__((ext_vector_type(8))) unsigned short u16x8;
typedef __attribute__((ext_vector_type(8))) __bf16 bf16x8;
typedef __attribute__((ext_vector_type(4))) float f32x4;
typedef __attribute__((ext_vector_type(16))) float f32x16;
typedef __attribute__((ext_vector_type(2))) int i32x2;

#define S_LEN 2048
#define HDIM 1024
#define NHEAD 16
#define HD 64
#define MTOK 4096            // B*S
#define QKV_STRIDE 4194304   // elements per q/k/v plane
#define LOG2E 1.44269504089f
#define QKSCL (0.125f * 1.44269504089f)

__device__ __forceinline__ float bf2f(u16 h) {
    unsigned u = ((unsigned)h) << 16;
    return __builtin_bit_cast(float, u);
}
__device__ __forceinline__ u16 f2bf(float f) {
    return __builtin_bit_cast(u16, (__bf16)f);   // native v_cvt, RNE
}
__device__ __forceinline__ bf16x8 as_bf16(u16x8 u) {
    union { u16x8 a; bf16x8 b; } c; c.a = u; return c.b;
}
__device__ __forceinline__ void gld_lds16(const u16* g, u16* l) {
    __builtin_amdgcn_global_load_lds((const __attribute__((address_space(1))) u16*)g,
                                     (__attribute__((address_space(3))) u16*)l, 16, 0, 0);
}

// exchange across lane<32 / lane>=32 halves
__device__ __forceinline__ void pl32swap(u32& a, u32& b) {
#if __has_builtin(__builtin_amdgcn_permlane32_swap)
    i32x2 r = __builtin_amdgcn_permlane32_swap((int)a, (int)b, false, false);
    a = (u32)r[0]; b = (u32)r[1];
#else
    u32 as = (u32)__shfl_xor((int)a, 32);
    u32 bs = (u32)__shfl_xor((int)b, 32);
    bool hi = (threadIdx.x & 32) != 0;
    u32 na = hi ? bs : a;
    u32 nb = hi ? b : as;
    a = na; b = nb;
#endif
}

// ---------------- fused preprocessing: casts + bias concat ----------------
__device__ __forceinline__ void cast4(const float* __restrict__ s, u16* __restrict__ d, int i) {
    f32x4 v = *(const f32x4*)(s + (size_t)i * 4);
    u16x4 o;
    o[0] = f2bf(v[0]); o[1] = f2bf(v[1]); o[2] = f2bf(v[2]); o[3] = f2bf(v[3]);
    *(u16x4*)(d + (size_t)i * 4) = o;
}

__global__ __launch_bounds__(256) void prep(const float* __restrict__ hs,
                                            const float* __restrict__ Wq, const float* __restrict__ Wk,
                                            const float* __restrict__ Wv, const float* __restrict__ Wd,
                                            const float* __restrict__ bq, const float* __restrict__ bk,
                                            const float* __restrict__ bv,
                                            u16* __restrict__ hsb, u16* __restrict__ wqkvb,
                                            u16* __restrict__ wdb, float* __restrict__ b3) {
    int bid = blockIdx.x, tid = threadIdx.x;
    if (bid < 4096) {
        cast4(hs, hsb, bid * 256 + tid);
    } else if (bid < 5120) {
        cast4(Wq, wqkvb, (bid - 4096) * 256 + tid);
    } else if (bid < 6144) {
        cast4(Wk, wqkvb + HDIM * HDIM, (bid - 5120) * 256 + tid);
    } else if (bid < 7168) {
        cast4(Wv, wqkvb + 2 * HDIM * HDIM, (bid - 6144) * 256 + tid);
    } else if (bid < 8192) {
        cast4(Wd, wdb, (bid - 7168) * 256 + tid);
    } else {
        int i = (bid - 8192) * 256 + tid;
        if (i < 3072) b3[i] = (i < 1024) ? bq[i] : (i < 2048) ? bk[i - 1024] : bv[i - 2048];
    }
}

// ---------------- QKV GEMM: 128x128, 2-phase (proven) ----------------
__global__ __launch_bounds__(256, 3) void gemm_qkv(const u16* __restrict__ A, const u16* __restrict__ Bw,
                                                   const float* __restrict__ bias,
                                                   u16* __restrict__ outb, u16* __restrict__ vtout) {
    __shared__ alignas(16) u16 As[2][128 * 32];
    __shared__ alignas(16) u16 Bs[2][128 * 32];
    const int Kd = 1024;
    const int tid = threadIdx.x;
    const int wave = tid >> 6, lane = tid & 63;
    const int l15 = lane & 15, l4 = lane >> 4;
    const int m0 = blockIdx.y * 128, n0 = blockIdx.x * 128;
    const int wm = wave >> 1, wn = wave & 1;

    const int cc0 = wave * 2;
    const int srow = lane >> 2;
    const int sco = (lane & 3) * 8;

    f32x4 acc[4][4];
#pragma unroll
    for (int i = 0; i < 4; i++)
#pragma unroll
        for (int j = 0; j < 4; j++) acc[i][j] = (f32x4){0.f, 0.f, 0.f, 0.f};

    auto STAGE = [&](int k0, int buf) {
#pragma unroll
        for (int i = 0; i < 2; i++) {
            int cc = cc0 + i;
            int row = cc * 16 + srow;
            gld_lds16(A + (size_t)(m0 + row) * Kd + k0 + sco, &As[buf][cc * 512]);
            gld_lds16(Bw + (size_t)(n0 + row) * Kd + k0 + sco, &Bs[buf][cc * 512]);
        }
    };

    const int nt = Kd >> 5;
    STAGE(0, 0);
    for (int t = 0; t < nt; ++t) {
        __builtin_amdgcn_s_barrier();
        if (t + 1 < nt) {
            STAGE((t + 1) << 5, (t + 1) & 1);
            asm volatile("s_waitcnt vmcnt(4)" ::: "memory");
        } else {
            asm volatile("s_waitcnt vmcnt(0)" ::: "memory");
        }
        __builtin_amdgcn_s_barrier();
        const u16* as = &As[t & 1][0];
        const u16* bs = &Bs[t & 1][0];
        bf16x8 af[4], bf[4];
#pragma unroll
        for (int x = 0; x < 4; x++) {
            af[x] = as_bf16(*(const u16x8*)&as[(wm * 64 + x * 16 + l15) * 32 + l4 * 8]);
            bf[x] = as_bf16(*(const u16x8*)&bs[(wn * 64 + x * 16 + l15) * 32 + l4 * 8]);
        }
        __builtin_amdgcn_s_setprio(1);
#pragma unroll
        for (int mi = 0; mi < 4; mi++)
#pragma unroll
            for (int nj = 0; nj < 4; nj++)
                acc[mi][nj] = __builtin_amdgcn_mfma_f32_16x16x32_bf16(af[mi], bf[nj], acc[mi][nj], 0, 0, 0);
        __builtin_amdgcn_s_setprio(0);
    }

#pragma unroll
    for (int mi = 0; mi < 4; mi++) {
#pragma unroll
        for (int nj = 0; nj < 4; nj++) {
            int coln = n0 + wn * 64 + nj * 16 + l15;
            float bv_ = bias[coln];
            int rowb = m0 + wm * 64 + mi * 16 + l4 * 4;
            int which = coln >> 10, nn = coln & 1023;
            int hh = nn >> 6, dd = nn & 63;
            int bb = rowb >> 11, ss = rowb & 2047;
            if (which < 2) {
#pragma unroll
                for (int r = 0; r < 4; r++)
                    outb[(size_t)which * QKV_STRIDE + ((size_t)((bb << 4) + hh) * S_LEN + ss + r) * HD + dd] =
                        f2bf(acc[mi][nj][r] + bv_);
            } else {
                u16x4 o;
#pragma unroll
                for (int r = 0; r < 4; r++) o[r] = f2bf(acc[mi][nj][r] + bv_);
                *(u16x4*)(vtout + ((size_t)((bb << 4) + hh) * HD + dd) * S_LEN + ss) = o;
            }
        }
    }
}

// ---------------- proj GEMM: 128x128, 2-phase, bf16 out ----------------
__global__ __launch_bounds__(256, 3) void gemm_proj(const u16* __restrict__ A, const u16* __restrict__ Bw,
                                                    const float* __restrict__ bias,
                                                    u16* __restrict__ outb, int Nd, int Kd) {
    __shared__ alignas(16) u16 As[2][128 * 32];
    __shared__ alignas(16) u16 Bs[2][128 * 32];
    const int tid = threadIdx.x;
    const int wave = tid >> 6, lane = tid & 63;
    const int l15 = lane & 15, l4 = lane >> 4;
    const int m0 = blockIdx.y * 128, n0 = blockIdx.x * 128;
    const int wm = wave >> 1, wn = wave & 1;

    const int cc0 = wave * 2;
    const int srow = lane >> 2;
    const int sco = (lane & 3) * 8;

    f32x4 acc[4][4];
#pragma unroll
    for (int i = 0; i < 4; i++)
#pragma unroll
        for (int j = 0; j < 4; j++) acc[i][j] = (f32x4){0.f, 0.f, 0.f, 0.f};

    auto STAGE = [&](int k0, int buf) {
#pragma unroll
        for (int i = 0; i < 2; i++) {
            int cc = cc0 + i;
            int row = cc * 16 + srow;
            gld_lds16(A + (size_t)(m0 + row) * Kd + k0 + sco, &As[buf][cc * 512]);
            gld_lds16(Bw + (size_t)(n0 + row) * Kd + k0 + sco, &Bs[buf][cc * 512]);
        }
    };

    const int nt = Kd >> 5;
    STAGE(0, 0);
    for (int t = 0; t < nt; ++t) {
        __builtin_amdgcn_s_barrier();
        if (t + 1 < nt) {
            STAGE((t + 1) << 5, (t + 1) & 1);
            asm volatile("s_waitcnt vmcnt(4)" ::: "memory");
        } else {
            asm volatile("s_waitcnt vmcnt(0)" ::: "memory");
        }
        __builtin_amdgcn_s_barrier();
        const u16* as = &As[t & 1][0];
        const u16* bs = &Bs[t & 1][0];
        bf16x8 af[4], bf[4];
#pragma unroll
        for (int x = 0; x < 4; x++) {
            af[x] = as_bf16(*(const u16x8*)&as[(wm * 64 + x * 16 + l15) * 32 + l4 * 8]);
            bf[x] = as_bf16(*(const u16x8*)&bs[(wn * 64 + x * 16 + l15) * 32 + l4 * 8]);
        }
        __builtin_amdgcn_s_setprio(1);
#pragma unroll
        for (int mi = 0; mi < 4; mi++)
#pragma unroll
            for (int nj = 0; nj < 4; nj++)
                acc[mi][nj] = __builtin_amdgcn_mfma_f32_16x16x32_bf16(af[mi], bf[nj], acc[mi][nj], 0, 0, 0);
        __builtin_amdgcn_s_setprio(0);
    }

#pragma unroll
    for (int mi = 0; mi < 4; mi++) {
#pragma unroll
        for (int nj = 0; nj < 4; nj++) {
            int coln = n0 + wn * 64 + nj * 16 + l15;
            float bv_ = bias[coln];
            int rowb = m0 + wm * 64 + mi * 16 + l4 * 4;
#pragma unroll
            for (int r = 0; r < 4; r++)
                outb[(size_t)(rowb + r) * Nd + coln] = f2bf(acc[mi][nj][r] + bv_);
        }
    }
}

// ---------------- flash attention v12: wave-private KV buffers, zero main-loop barriers (FIXED units) ----------------
// grid 256 (1 block/CU), 512 thr = 4 q-strips x 2 kv-groups. 64 q/wave, KVT=32.
// Per wave: 2 private bufs of (K 2048 + V 2048) u16. Per-wave counted vmcnt only.
__global__ __launch_bounds__(512, 1) void flash_attn12(const u16* __restrict__ qkv,
                                                       const u16* __restrict__ vt,
                                                       const float* __restrict__ amask,
                                                       u16* __restrict__ ctx) {
    // u16 layout: wave w owns [w*8192, w*8192+8192): buf b at +b*4096 (K 2048 | V 2048).
    // mask bf16[2048] at u16 offset 65536 (byte 131072). total 135168 B.
    // epilogue alias: Oex f32 [4 ws][64 d][64 q] at byte 0 (64KB); lsum at byte 65536.
    __shared__ alignas(16) char smem[135168];
    u16* smem16 = (u16*)smem;

    const int tid = threadIdx.x;
    const int wave = tid >> 6, lane = tid & 63;
    const int l31 = lane & 31;
    const int hi = lane >> 5;
    const int hi4 = hi * 4;
    const int g = wave >> 2;            // kv-half group
    const int ws = wave & 3;            // q-strip

    // XCD-aware: XCD (lid&7) owns heads 4x..4x+3; 8 q-blocks of 256 rows
    const int lid = blockIdx.x;
    const int idx = lid >> 3;                      // 0..31
    const int bh = (lid & 7) * 4 + (idx >> 3);     // 0..31
    const int qb = idx & 7;
    const int b = bh >> 4, h = bh & 15;
    const int qr0 = qb * 256 + ws * 64;            // this wave's first q-row

    const u16* qh = qkv + (size_t)bh * (S_LEN * HD);
    const u16* kh = qh + QKV_STRIDE;
    const u16* vth = vt + (size_t)bh * (S_LEN * HD);   // V^T [64][2048]

    u16* Mlb = smem16 + 65536;

    // mask -> LDS bf16, pre-scaled by log2(e)
    {
        f32x4 m = *(const f32x4*)(amask + (size_t)b * S_LEN + tid * 4);
        u16x4 mm;
#pragma unroll
        for (int j = 0; j < 4; j++) mm[j] = f2bf(m[j] * LOG2E);
        *(u16x4*)&Mlb[tid * 4] = mm;
    }

    // Q B-fragments for both column groups
    bf16x8 qf0[4], qf1[4];
#pragma unroll
    for (int s = 0; s < 4; ++s) {
        qf0[s] = as_bf16(*(const u16x8*)(qh + (size_t)(qr0 + l31) * HD + s * 16 + hi * 8));
        qf1[s] = as_bf16(*(const u16x8*)(qh + (size_t)(qr0 + 32 + l31) * HD + s * 16 + hi * 8));
    }

    __syncthreads();   // mask visible; drains vmcnt (clean per-wave FIFO before counted staging)

    // wave-private buffers (u16 units)
    u16* wbase = smem16 + wave * 8192;

    // staging sources (pre-swizzled chunk, LDS linear dest).
    // K: [32 kv][64 d], 4 loads x 8 rows; lane: row lane>>3, chunk (lane&7)^(lane>>3)  [key kv&7]
    const int ksc8 = ((lane & 7) ^ (lane >> 3)) * 8;
    const u16* kss = kh + (size_t)(g * 1024 + (lane >> 3)) * HD + ksc8;
    // V^T: [64 d][32 kv], 4 loads x 16 d-rows; lane: row lane>>2, chunk (lane&3)^((lane>>2)&3) [key d&3]
    const int vsc8 = ((lane & 3) ^ ((lane >> 2) & 3)) * 8;
    const u16* vss = vth + (size_t)(lane >> 2) * S_LEN + g * 1024 + vsc8;

    f32x16 oacc00, oacc01, oacc10, oacc11;   // [qgrp][dsub]
#pragma unroll
    for (int i = 0; i < 16; ++i) { oacc00[i] = 0.f; oacc01[i] = 0.f; oacc10[i] = 0.f; oacc11[i] = 0.f; }
    float l_run0 = 0.f, l_run1 = 0.f;

    auto STAGE = [&](int t, int buf) {     // 8 gld_lds16, each writes 512 u16; wave-private
        u16* kd = wbase + buf * 4096;
        u16* vd = kd + 2048;
        const u16* ks = kss + (size_t)t * 32 * HD;
        const u16* vs = vss + t * 32;
#pragma unroll
        for (int j = 0; j < 4; ++j)
            gld_lds16(ks + (size_t)j * 8 * HD, kd + j * 512);
#pragma unroll
        for (int j = 0; j < 4; ++j)
            gld_lds16(vs + (size_t)j * 16 * S_LEN, vd + j * 512);
    };

    auto tile = [&](int t, int buf) {
        const u16* kb = wbase + buf * 4096;   // [32 kv][64 d], chunk8 XOR'd by kv&7
        const u16* vb = kb + 2048;            // [64 d][32 kv], chunk4 XOR'd by d&3
        const int kv0 = g * 1024 + t * 32;
        // QK^T swapped: S^T[32 kv][32 q] x 2 column groups, shared kf
        f32x16 acc0, acc1;
#pragma unroll
        for (int i = 0; i < 16; ++i) { acc0[i] = 0.f; acc1[i] = 0.f; }
        const int ksw = (l31 & 7) << 3;
        __builtin_amdgcn_s_setprio(1);
#pragma unroll
        for (int s = 0; s < 4; ++s) {
            bf16x8 kf = as_bf16(*(const u16x8*)&kb[l31 * 64 + ((((s * 2 + hi) << 3)) ^ ksw)]);
            acc0 = __builtin_amdgcn_mfma_f32_32x32x16_bf16(kf, qf0[s], acc0, 0, 0, 0);
            acc1 = __builtin_amdgcn_mfma_f32_32x32x16_bf16(kf, qf1[s], acc1, 0, 0, 0);
        }
        __builtin_amdgcn_s_setprio(0);
        // softmax both groups: lane owns q; reg rg*4+rr -> kv = rg*8 + hi*4 + rr
        u32 pw0[8], pw1[8];
#pragma unroll
        for (int rg = 0; rg < 4; ++rg) {
            u16x4 mraw = *(const u16x4*)&Mlb[kv0 + rg * 8 + hi4];
#pragma unroll
            for (int r2 = 0; r2 < 2; ++r2) {
                float m0 = bf2f(mraw[r2 * 2]), m1 = bf2f(mraw[r2 * 2 + 1]);
                float pa0 = __builtin_amdgcn_exp2f(acc0[rg * 4 + r2 * 2] * QKSCL + m0);
                float pb0 = __builtin_amdgcn_exp2f(acc0[rg * 4 + r2 * 2 + 1] * QKSCL + m1);
                float pa1 = __builtin_amdgcn_exp2f(acc1[rg * 4 + r2 * 2] * QKSCL + m0);
                float pb1 = __builtin_amdgcn_exp2f(acc1[rg * 4 + r2 * 2 + 1] * QKSCL + m1);
                l_run0 += pa0 + pb0;
                l_run1 += pa1 + pb1;
                pw0[rg * 2 + r2] = (u32)f2bf(pa0) | ((u32)f2bf(pb0) << 16);
                pw1[rg * 2 + r2] = (u32)f2bf(pa1) | ((u32)f2bf(pb1) << 16);
            }
        }
        // in-register P^T B-frags via lane<32/lane>=32 swap
        pl32swap(pw0[0], pw0[2]); pl32swap(pw0[1], pw0[3]);
        pl32swap(pw0[4], pw0[6]); pl32swap(pw0[5], pw0[7]);
        pl32swap(pw1[0], pw1[2]); pl32swap(pw1[1], pw1[3]);
        pl32swap(pw1[4], pw1[6]); pl32swap(pw1[5], pw1[7]);
        union { u32 w[4]; u16x8 v; } u0a, u0b, u1a, u1b;
        u0a.w[0] = pw0[0]; u0a.w[1] = pw0[1]; u0a.w[2] = pw0[2]; u0a.w[3] = pw0[3];
        u0b.w[0] = pw0[4]; u0b.w[1] = pw0[5]; u0b.w[2] = pw0[6]; u0b.w[3] = pw0[7];
        u1a.w[0] = pw1[0]; u1a.w[1] = pw1[1]; u1a.w[2] = pw1[2]; u1a.w[3] = pw1[3];
        u1b.w[0] = pw1[4]; u1b.w[1] = pw1[5]; u1b.w[2] = pw1[6]; u1b.w[3] = pw1[7];
        bf16x8 pf0a = as_bf16(u0a.v), pf0b = as_bf16(u0b.v);
        bf16x8 pf1a = as_bf16(u1a.v), pf1b = as_bf16(u1b.v);
        // PV swapped: O^T[d][q] += V^T[d][kv] * P^T[kv][q]; kv k-step chunks {hi, 2+hi}; shared vf
        __builtin_amdgcn_s_setprio(1);
        {
            const int dr0 = l31, sw0 = dr0 & 3;
            const int dr1 = 32 + l31, sw1 = dr1 & 3;
            bf16x8 vf;
            vf = as_bf16(*(const u16x8*)&vb[dr0 * 32 + ((hi ^ sw0) << 3)]);
            oacc00 = __builtin_amdgcn_mfma_f32_32x32x16_bf16(vf, pf0a, oacc00, 0, 0, 0);
            oacc10 = __builtin_amdgcn_mfma_f32_32x32x16_bf16(vf, pf1a, oacc10, 0, 0, 0);
            vf = as_bf16(*(const u16x8*)&vb[dr0 * 32 + (((2 + hi) ^ sw0) << 3)]);
            oacc00 = __builtin_amdgcn_mfma_f32_32x32x16_bf16(vf, pf0b, oacc00, 0, 0, 0);
            oacc10 = __builtin_amdgcn_mfma_f32_32x32x16_bf16(vf, pf1b, oacc10, 0, 0, 0);
            vf = as_bf16(*(const u16x8*)&vb[dr1 * 32 + ((hi ^ sw1) << 3)]);
            oacc01 = __builtin_amdgcn_mfma_f32_32x32x16_bf16(vf, pf0a, oacc01, 0, 0, 0);
            oacc11 = __builtin_amdgcn_mfma_f32_32x32x16_bf16(vf, pf1a, oacc11, 0, 0, 0);
            vf = as_bf16(*(const u16x8*)&vb[dr1 * 32 + (((2 + hi) ^ sw1) << 3)]);
            oacc01 = __builtin_amdgcn_mfma_f32_32x32x16_bf16(vf, pf0b, oacc01, 0, 0, 0);
            oacc11 = __builtin_amdgcn_mfma_f32_32x32x16_bf16(vf, pf1b, oacc11, 0, 0, 0);
        }
        __builtin_amdgcn_s_setprio(0);
    };

    // wave-private pipeline: 2 tiles (16 loads) in flight, no block barriers
    STAGE(0, 0);
    STAGE(1, 1);
    for (int t = 0; t < 32; ++t) {
        if (t < 31) {
            asm volatile("s_waitcnt vmcnt(8)" ::: "memory");   // this wave's tile-t loads landed
        } else {
            asm volatile("s_waitcnt vmcnt(0)" ::: "memory");
        }
        tile(t, t & 1);
        if (t + 2 < 32) {
            // guard: this wave's ds_reads of buffer (t&1) must complete before overwrite
            asm volatile("s_waitcnt lgkmcnt(0)" ::: "memory");
            __builtin_amdgcn_sched_barrier(0);
            STAGE(t + 2, t & 1);
        }
    }

    // ---- combine kv-groups through LDS ----
    float l0 = l_run0 + __shfl_xor(l_run0, 32);
    float l1 = l_run1 + __shfl_xor(l_run1, 32);
    __syncthreads();
    float* Oex = (float*)smem;                  // [4 ws][64 d][64 q]
    float* lsum = (float*)(smem + 65536);       // [4 ws][64 q] — overlaps waves 4..7 bufs (post-sync OK)
    if (g == 1) {
#pragma unroll
        for (int rg = 0; rg < 4; ++rg)
#pragma unroll
            for (int rr = 0; rr < 4; ++rr) {
                int dA = hi4 + 8 * rg + rr;          // dsub 0
                int dB = 32 + hi4 + 8 * rg + rr;     // dsub 1
                Oex[ws * 4096 + dA * 64 + l31]      = oacc00[rg * 4 + rr];
                Oex[ws * 4096 + dB * 64 + l31]      = oacc01[rg * 4 + rr];
                Oex[ws * 4096 + dA * 64 + 32 + l31] = oacc10[rg * 4 + rr];
                Oex[ws * 4096 + dB * 64 + 32 + l31] = oacc11[rg * 4 + rr];
            }
        if (lane < 32) { lsum[ws * 64 + l31] = l0; lsum[ws * 64 + 32 + l31] = l1; }
    }
    __syncthreads();
    if (g == 0) {
        float inv0 = 1.0f / (l0 + lsum[ws * 64 + l31]);
        float inv1 = 1.0f / (l1 + lsum[ws * 64 + 32 + l31]);
        u16* cp0 = ctx + ((size_t)b * S_LEN + qr0 + l31) * HDIM + h * HD;
        u16* cp1 = ctx + ((size_t)b * S_LEN + qr0 + 32 + l31) * HDIM + h * HD;
#pragma unroll
        for (int rg = 0; rg < 4; ++rg) {
            u16x4 oA0, oB0, oA1, oB1;
#pragma unroll
            for (int rr = 0; rr < 4; ++rr) {
                int dA = hi4 + 8 * rg + rr;
                int dB = 32 + hi4 + 8 * rg + rr;
                oA0[rr] = f2bf((oacc00[rg * 4 + rr] + Oex[ws * 4096 + dA * 64 + l31]) * inv0);
                oB0[rr] = f2bf((oacc01[rg * 4 + rr] + Oex[ws * 4096 + dB * 64 + l31]) * inv0);
                oA1[rr] = f2bf((oacc10[rg * 4 + rr] + Oex[ws * 4096 + dA * 64 + 32 + l31]) * inv1);
                oB1[rr] = f2bf((oacc11[rg * 4 + rr] + Oex[ws * 4096 + dB * 64 + 32 + l31]) * inv1);
            }
            *(u16x4*)(cp0 + hi4 + 8 * rg) = oA0;
            *(u16x4*)(cp0 + 32 + hi4 + 8 * rg) = oB0;
            *(u16x4*)(cp1 + hi4 + 8 * rg) = oA1;
            *(u16x4*)(cp1 + 32 + hi4 + 8 * rg) = oB1;
        }
    }
}

// ---------------- residual + layernorm (proj in bf16) ----------------
__global__ __launch_bounds__(256) void resid_ln(const float* __restrict__ hs, const u16* __restrict__ proj,
                                                const float* __restrict__ g, const float* __restrict__ be,
                                                float* __restrict__ out) {
    int row = blockIdx.x, tid = threadIdx.x;
    int base = row * HDIM + tid * 4;
    f32x4 a = *(const f32x4*)(hs + base);
    u16x4 pb = *(const u16x4*)(proj + base);
    f32x4 x;
#pragma unroll
    for (int j = 0; j < 4; j++) x[j] = a[j] + bf2f(pb[j]);
    float s = x[0] + x[1] + x[2] + x[3];
    float sq = x[0] * x[0] + x[1] * x[1] + x[2] * x[2] + x[3] * x[3];
#pragma unroll
    for (int m = 1; m < 64; m <<= 1) {
        s += __shfl_xor(s, m);
        sq += __shfl_xor(sq, m);
    }
    __shared__ float red[8];
    int wave = tid >> 6, lane = tid & 63;
    if (lane == 0) { red[wave] = s; red[4 + wave] = sq; }
    __syncthreads();
    s = red[0] + red[1] + red[2] + red[3];
    sq = red[4] + red[5] + red[6] + red[7];
    float mean = s * (1.0f / 1024.0f);
    float var = sq * (1.0f / 1024.0f) - mean * mean;
    float rstd = rsqrtf(fmaxf(var, 0.f) + 1e-12f);
    f32x4 gg = *(const f32x4*)(g + tid * 4);
    f32x4 bb = *(const f32x4*)(be + tid * 4);
    f32x4 o;
#pragma unroll
    for (int j = 0; j < 4; j++) o[j] = (x[j] - mean) * rstd * gg[j] + bb[j];
    *(f32x4*)(out + base) = o;
}

extern "C" void kernel_launch(void* const* d_in, const int* in_sizes, int n_in,
                              void* d_out, int out_size, void* d_ws, size_t ws_size,
                              hipStream_t stream) {
    const float* hs    = (const float*)d_in[0];
    const float* amask = (const float*)d_in[1];
    const float* Wq    = (const float*)d_in[2];
    const float* bq    = (const float*)d_in[3];
    const float* Wk    = (const float*)d_in[4];
    const float* bk    = (const float*)d_in[5];
    const float* Wv    = (const float*)d_in[6];
    const float* bv    = (const float*)d_in[7];
    const float* Wd    = (const float*)d_in[8];
    const float* bd    = (const float*)d_in[9];
    const float* gamma = (const float*)d_in[10];
    const float* beta  = (const float*)d_in[11];

    char* ws = (char*)d_ws;
    u16*   hsb   = (u16*)(ws);                       // 8 MB
    u16*   Wqkvb = (u16*)(ws + ((size_t)8 << 20));   // 6 MB
    u16*   Wdb   = (u16*)(ws + ((size_t)14 << 20));  // 2 MB
    u16*   qkv   = (u16*)(ws + ((size_t)16 << 20));  // q,k planes; plane 2 = V^T
    u16*   vt    = qkv + 2 * (size_t)QKV_STRIDE;
    u16*   ctx   = (u16*)(ws + ((size_t)40 << 20));  // 8 MB
    u16*   projb = (u16*)(ws + ((size_t)48 << 20));  // 8 MB bf16
    float* b3    = (float*)(ws + ((size_t)64 << 20));// 12 KB

    prep<<<8204, 256, 0, stream>>>(hs, Wq, Wk, Wv, Wd, bq, bk, bv, hsb, Wqkvb, Wdb, b3);

    // QKV projection: [4096,1024] x [3072,1024]^T, 768 balanced blocks
    gemm_qkv<<<dim3(24, 32), 256, 0, stream>>>(hsb, Wqkvb, b3, qkv, vt);

    // attention
    flash_attn12<<<256, 512, 0, stream>>>(qkv, vt, amask, ctx);

    // output projection -> bf16
    gemm_proj<<<dim3(8, 32), 256, 0, stream>>>(ctx, Wdb, bd, projb, HDIM, HDIM);

    // residual + layernorm
    resid_ln<<<MTOK, 256, 0, stream>>>(hs, projb, gamma, beta, (float*)d_out);
}

// Round 14
// 125.014 us; speedup vs baseline: 1.0475x; 1.0475x over previous
//
#include <hip/hip_runtime.h>

typedef unsigned short u16;
typedef unsigned int u32;
typedef __attribute__((ext_vector_type(4))) unsigned short u16x4;
typedef __attribute__((ext_vector_type(8))) unsigned short u16x8;
typedef __attribute__((ext_vector_type(8))) __bf16 bf16x8;
typedef __attribute__((ext_vector_type(4))) float f32x4;
typedef __attribute__((ext_vector_type(16))) float f32x16;
typedef __attribute__((ext_vector_type(2))) int i32x2;

#define S_LEN 2048
#define HDIM 1024
#define NHEAD 16
#define HD 64
#define MTOK 4096            // B*S
#define QKV_STRIDE 4194304   // elements per q/k/v plane
#define LOG2E 1.44269504089f
#define QKSCL (0.125f * 1.44269504089f)

__device__ __forceinline__ float bf2f(u16 h) {
    unsigned u = ((unsigned)h) << 16;
    return __builtin_bit_cast(float, u);
}
__device__ __forceinline__ u16 f2bf(float f) {
    return __builtin_bit_cast(u16, (__bf16)f);   // native v_cvt, RNE
}
__device__ __forceinline__ bf16x8 as_bf16(u16x8 u) {
    union { u16x8 a; bf16x8 b; } c; c.a = u; return c.b;
}
__device__ __forceinline__ void gld_lds16(const u16* g, u16* l) {
    __builtin_amdgcn_global_load_lds((const __attribute__((address_space(1))) u16*)g,
                                     (__attribute__((address_space(3))) u16*)l, 16, 0, 0);
}

// exchange across lane<32 / lane>=32 halves
__device__ __forceinline__ void pl32swap(u32& a, u32& b) {
#if __has_builtin(__builtin_amdgcn_permlane32_swap)
    i32x2 r = __builtin_amdgcn_permlane32_swap((int)a, (int)b, false, false);
    a = (u32)r[0]; b = (u32)r[1];
#else
    u32 as = (u32)__shfl_xor((int)a, 32);
    u32 bs = (u32)__shfl_xor((int)b, 32);
    bool hi = (threadIdx.x & 32) != 0;
    u32 na = hi ? bs : a;
    u32 nb = hi ? b : as;
    a = na; b = nb;
#endif
}

// ---------------- fused preprocessing: casts + bias concat (8 elems/thread) ----------------
__device__ __forceinline__ void cast8(const float* __restrict__ s, u16* __restrict__ d, int i) {
    f32x4 v0 = *(const f32x4*)(s + (size_t)i * 8);
    f32x4 v1 = *(const f32x4*)(s + (size_t)i * 8 + 4);
    u16x8 o;
#pragma unroll
    for (int j = 0; j < 4; j++) { o[j] = f2bf(v0[j]); o[4 + j] = f2bf(v1[j]); }
    *(u16x8*)(d + (size_t)i * 8) = o;
}

__global__ __launch_bounds__(256) void prep(const float* __restrict__ hs,
                                            const float* __restrict__ Wq, const float* __restrict__ Wk,
                                            const float* __restrict__ Wv, const float* __restrict__ Wd,
                                            const float* __restrict__ bq, const float* __restrict__ bk,
                                            const float* __restrict__ bv,
                                            u16* __restrict__ hsb, u16* __restrict__ wqkvb,
                                            u16* __restrict__ wdb, float* __restrict__ b3) {
    int bid = blockIdx.x, tid = threadIdx.x;
    if (bid < 2048) {
        cast8(hs, hsb, bid * 256 + tid);
    } else if (bid < 2560) {
        cast8(Wq, wqkvb, (bid - 2048) * 256 + tid);
    } else if (bid < 3072) {
        cast8(Wk, wqkvb + HDIM * HDIM, (bid - 2560) * 256 + tid);
    } else if (bid < 3584) {
        cast8(Wv, wqkvb + 2 * HDIM * HDIM, (bid - 3072) * 256 + tid);
    } else if (bid < 4096) {
        cast8(Wd, wdb, (bid - 3584) * 256 + tid);
    } else {
        int i = (bid - 4096) * 256 + tid;
        if (i < 3072) b3[i] = (i < 1024) ? bq[i] : (i < 2048) ? bk[i - 1024] : bv[i - 2048];
    }
}

// ---------------- QKV GEMM: 128x128, 2-phase (proven) ----------------
__global__ __launch_bounds__(256, 3) void gemm_qkv(const u16* __restrict__ A, const u16* __restrict__ Bw,
                                                   const float* __restrict__ bias,
                                                   u16* __restrict__ outb, u16* __restrict__ vtout) {
    __shared__ alignas(16) u16 As[2][128 * 32];
    __shared__ alignas(16) u16 Bs[2][128 * 32];
    const int Kd = 1024;
    const int tid = threadIdx.x;
    const int wave = tid >> 6, lane = tid & 63;
    const int l15 = lane & 15, l4 = lane >> 4;
    const int m0 = blockIdx.y * 128, n0 = blockIdx.x * 128;
    const int wm = wave >> 1, wn = wave & 1;

    const int cc0 = wave * 2;
    const int srow = lane >> 2;
    const int sco = (lane & 3) * 8;

    f32x4 acc[4][4];
#pragma unroll
    for (int i = 0; i < 4; i++)
#pragma unroll
        for (int j = 0; j < 4; j++) acc[i][j] = (f32x4){0.f, 0.f, 0.f, 0.f};

    auto STAGE = [&](int k0, int buf) {
#pragma unroll
        for (int i = 0; i < 2; i++) {
            int cc = cc0 + i;
            int row = cc * 16 + srow;
            gld_lds16(A + (size_t)(m0 + row) * Kd + k0 + sco, &As[buf][cc * 512]);
            gld_lds16(Bw + (size_t)(n0 + row) * Kd + k0 + sco, &Bs[buf][cc * 512]);
        }
    };

    const int nt = Kd >> 5;
    STAGE(0, 0);
    for (int t = 0; t < nt; ++t) {
        __builtin_amdgcn_s_barrier();
        if (t + 1 < nt) {
            STAGE((t + 1) << 5, (t + 1) & 1);
            asm volatile("s_waitcnt vmcnt(4)" ::: "memory");
        } else {
            asm volatile("s_waitcnt vmcnt(0)" ::: "memory");
        }
        __builtin_amdgcn_s_barrier();
        const u16* as = &As[t & 1][0];
        const u16* bs = &Bs[t & 1][0];
        bf16x8 af[4], bf[4];
#pragma unroll
        for (int x = 0; x < 4; x++) {
            af[x] = as_bf16(*(const u16x8*)&as[(wm * 64 + x * 16 + l15) * 32 + l4 * 8]);
            bf[x] = as_bf16(*(const u16x8*)&bs[(wn * 64 + x * 16 + l15) * 32 + l4 * 8]);
        }
        __builtin_amdgcn_s_setprio(1);
#pragma unroll
        for (int mi = 0; mi < 4; mi++)
#pragma unroll
            for (int nj = 0; nj < 4; nj++)
                acc[mi][nj] = __builtin_amdgcn_mfma_f32_16x16x32_bf16(af[mi], bf[nj], acc[mi][nj], 0, 0, 0);
        __builtin_amdgcn_s_setprio(0);
    }

#pragma unroll
    for (int mi = 0; mi < 4; mi++) {
#pragma unroll
        for (int nj = 0; nj < 4; nj++) {
            int coln = n0 + wn * 64 + nj * 16 + l15;
            float bv_ = bias[coln];
            int rowb = m0 + wm * 64 + mi * 16 + l4 * 4;
            int which = coln >> 10, nn = coln & 1023;
            int hh = nn >> 6, dd = nn & 63;
            int bb = rowb >> 11, ss = rowb & 2047;
            if (which < 2) {
#pragma unroll
                for (int r = 0; r < 4; r++)
                    outb[(size_t)which * QKV_STRIDE + ((size_t)((bb << 4) + hh) * S_LEN + ss + r) * HD + dd] =
                        f2bf(acc[mi][nj][r] + bv_);
            } else {
                u16x4 o;
#pragma unroll
                for (int r = 0; r < 4; r++) o[r] = f2bf(acc[mi][nj][r] + bv_);
                *(u16x4*)(vtout + ((size_t)((bb << 4) + hh) * HD + dd) * S_LEN + ss) = o;
            }
        }
    }
}

// ---------------- proj GEMM: 128x128, 2-phase, bf16 out ----------------
__global__ __launch_bounds__(256, 3) void gemm_proj(const u16* __restrict__ A, const u16* __restrict__ Bw,
                                                    const float* __restrict__ bias,
                                                    u16* __restrict__ outb, int Nd, int Kd) {
    __shared__ alignas(16) u16 As[2][128 * 32];
    __shared__ alignas(16) u16 Bs[2][128 * 32];
    const int tid = threadIdx.x;
    const int wave = tid >> 6, lane = tid & 63;
    const int l15 = lane & 15, l4 = lane >> 4;
    const int m0 = blockIdx.y * 128, n0 = blockIdx.x * 128;
    const int wm = wave >> 1, wn = wave & 1;

    const int cc0 = wave * 2;
    const int srow = lane >> 2;
    const int sco = (lane & 3) * 8;

    f32x4 acc[4][4];
#pragma unroll
    for (int i = 0; i < 4; i++)
#pragma unroll
        for (int j = 0; j < 4; j++) acc[i][j] = (f32x4){0.f, 0.f, 0.f, 0.f};

    auto STAGE = [&](int k0, int buf) {
#pragma unroll
        for (int i = 0; i < 2; i++) {
            int cc = cc0 + i;
            int row = cc * 16 + srow;
            gld_lds16(A + (size_t)(m0 + row) * Kd + k0 + sco, &As[buf][cc * 512]);
            gld_lds16(Bw + (size_t)(n0 + row) * Kd + k0 + sco, &Bs[buf][cc * 512]);
        }
    };

    const int nt = Kd >> 5;
    STAGE(0, 0);
    for (int t = 0; t < nt; ++t) {
        __builtin_amdgcn_s_barrier();
        if (t + 1 < nt) {
            STAGE((t + 1) << 5, (t + 1) & 1);
            asm volatile("s_waitcnt vmcnt(4)" ::: "memory");
        } else {
            asm volatile("s_waitcnt vmcnt(0)" ::: "memory");
        }
        __builtin_amdgcn_s_barrier();
        const u16* as = &As[t & 1][0];
        const u16* bs = &Bs[t & 1][0];
        bf16x8 af[4], bf[4];
#pragma unroll
        for (int x = 0; x < 4; x++) {
            af[x] = as_bf16(*(const u16x8*)&as[(wm * 64 + x * 16 + l15) * 32 + l4 * 8]);
            bf[x] = as_bf16(*(const u16x8*)&bs[(wn * 64 + x * 16 + l15) * 32 + l4 * 8]);
        }
        __builtin_amdgcn_s_setprio(1);
#pragma unroll
        for (int mi = 0; mi < 4; mi++)
#pragma unroll
            for (int nj = 0; nj < 4; nj++)
                acc[mi][nj] = __builtin_amdgcn_mfma_f32_16x16x32_bf16(af[mi], bf[nj], acc[mi][nj], 0, 0, 0);
        __builtin_amdgcn_s_setprio(0);
    }

#pragma unroll
    for (int mi = 0; mi < 4; mi++) {
#pragma unroll
        for (int nj = 0; nj < 4; nj++) {
            int coln = n0 + wn * 64 + nj * 16 + l15;
            float bv_ = bias[coln];
            int rowb = m0 + wm * 64 + mi * 16 + l4 * 4;
#pragma unroll
            for (int r = 0; r < 4; r++)
                outb[(size_t)(rowb + r) * Nd + coln] = f2bf(acc[mi][nj][r] + bv_);
        }
    }
}

// ---------------- flash attention v10 (best measured: 55.4us, frozen) ----------------
// grid 256 (1 block/CU), 512 threads = 2 kv-groups x 4 strips. Per wave: 64 q x 1024 kv.
__global__ __launch_bounds__(512, 2) void flash_attn10(const u16* __restrict__ qkv,
                                                       const u16* __restrict__ vt,
                                                       const float* __restrict__ amask,
                                                       u16* __restrict__ ctx) {
    __shared__ alignas(16) char smem[102400];

    const int tid = threadIdx.x;
    const int wave = tid >> 6, lane = tid & 63;
    const int l31 = lane & 31;
    const int hi = lane >> 5;
    const int hi4 = hi * 4;
    const int g = wave >> 2;            // kv-half group
    const int ws = wave & 3;            // q-strip

    const int lid = blockIdx.x;
    const int idx = lid >> 3;                      // 0..31
    const int bh = (lid & 7) * 4 + (idx >> 3);     // 0..31
    const int qb = idx & 7;
    const int b = bh >> 4, h = bh & 15;
    const int qr0 = qb * 256 + ws * 64;            // this wave's first q-row

    const u16* qh = qkv + (size_t)bh * (S_LEN * HD);
    const u16* kh = qh + QKV_STRIDE;
    const u16* vth = vt + (size_t)bh * (S_LEN * HD);   // V^T [64][2048]

    u16* Mlb = (u16*)(smem + 98304);

    // mask -> LDS bf16, pre-scaled by log2(e)
    {
        f32x4 m = *(const f32x4*)(amask + (size_t)b * S_LEN + tid * 4);
        u16x4 mm;
#pragma unroll
        for (int j = 0; j < 4; j++) mm[j] = f2bf(m[j] * LOG2E);
        *(u16x4*)&Mlb[tid * 4] = mm;
    }

    // Q B-fragments for both column groups
    bf16x8 qf0[4], qf1[4];
#pragma unroll
    for (int s = 0; s < 4; ++s) {
        qf0[s] = as_bf16(*(const u16x8*)(qh + (size_t)(qr0 + l31) * HD + s * 16 + hi * 8));
        qf1[s] = as_bf16(*(const u16x8*)(qh + (size_t)(qr0 + 32 + l31) * HD + s * 16 + hi * 8));
    }

    __syncthreads();

    const int srow = lane >> 3;
    const int schunk = (lane & 7) ^ srow;
    const u16* kss = kh + (size_t)(g * 1024 + ws * 16 + srow) * HD + schunk * 8;
    const u16* vss = vth + (size_t)(ws * 16 + srow) * S_LEN + g * 1024 + schunk * 8;

    f32x16 oacc00, oacc01, oacc10, oacc11;
#pragma unroll
    for (int i = 0; i < 16; ++i) { oacc00[i] = 0.f; oacc01[i] = 0.f; oacc10[i] = 0.f; oacc11[i] = 0.f; }
    float l_run0 = 0.f, l_run1 = 0.f;

    auto STAGE = [&](int t, int buf) {
        u16* base = (u16*)(smem + g * 49152 + buf * 16384);
        u16* kd = base + ws * 1024;
        u16* vd = base + 4096 + ws * 1024;
        const u16* ks = kss + (size_t)t * 64 * HD;
        const u16* vs = vss + t * 64;
        gld_lds16(ks, kd);
        gld_lds16(ks + 8 * HD, kd + 512);
        gld_lds16(vs, vd);
        gld_lds16(vs + 8 * S_LEN, vd + 512);
    };

    auto tile = [&](int t, int buf) {
        const u16* kb = (const u16*)(smem + g * 49152 + buf * 16384);
        const u16* vb = kb + 4096;
        const int kv0 = g * 1024 + t * 64;
#pragma unroll
        for (int sub = 0; sub < 2; ++sub) {
            f32x16 acc0, acc1;
#pragma unroll
            for (int i = 0; i < 16; ++i) { acc0[i] = 0.f; acc1[i] = 0.f; }
            const int kvrow = sub * 32 + l31;
            const int ksw = (kvrow & 7) << 3;
            __builtin_amdgcn_s_setprio(1);
#pragma unroll
            for (int s = 0; s < 4; ++s) {
                bf16x8 kf = as_bf16(*(const u16x8*)&kb[kvrow * 64 + (((s * 2 + hi) << 3) ^ ksw)]);
                acc0 = __builtin_amdgcn_mfma_f32_32x32x16_bf16(kf, qf0[s], acc0, 0, 0, 0);
                acc1 = __builtin_amdgcn_mfma_f32_32x32x16_bf16(kf, qf1[s], acc1, 0, 0, 0);
            }
            __builtin_amdgcn_s_setprio(0);
            u32 pw0[8], pw1[8];
#pragma unroll
            for (int rg = 0; rg < 4; ++rg) {
                u16x4 mraw = *(const u16x4*)&Mlb[kv0 + sub * 32 + rg * 8 + hi4];
#pragma unroll
                for (int r2 = 0; r2 < 2; ++r2) {
                    float m0 = bf2f(mraw[r2 * 2]), m1 = bf2f(mraw[r2 * 2 + 1]);
                    float pa0 = __builtin_amdgcn_exp2f(acc0[rg * 4 + r2 * 2] * QKSCL + m0);
                    float pb0 = __builtin_amdgcn_exp2f(acc0[rg * 4 + r2 * 2 + 1] * QKSCL + m1);
                    float pa1 = __builtin_amdgcn_exp2f(acc1[rg * 4 + r2 * 2] * QKSCL + m0);
                    float pb1 = __builtin_amdgcn_exp2f(acc1[rg * 4 + r2 * 2 + 1] * QKSCL + m1);
                    l_run0 += pa0 + pb0;
                    l_run1 += pa1 + pb1;
                    pw0[rg * 2 + r2] = (u32)f2bf(pa0) | ((u32)f2bf(pb0) << 16);
                    pw1[rg * 2 + r2] = (u32)f2bf(pa1) | ((u32)f2bf(pb1) << 16);
                }
            }
            pl32swap(pw0[0], pw0[2]); pl32swap(pw0[1], pw0[3]);
            pl32swap(pw0[4], pw0[6]); pl32swap(pw0[5], pw0[7]);
            pl32swap(pw1[0], pw1[2]); pl32swap(pw1[1], pw1[3]);
            pl32swap(pw1[4], pw1[6]); pl32swap(pw1[5], pw1[7]);
            union { u32 w[4]; u16x8 v; } u0a, u0b, u1a, u1b;
            u0a.w[0] = pw0[0]; u0a.w[1] = pw0[1]; u0a.w[2] = pw0[2]; u0a.w[3] = pw0[3];
            u0b.w[0] = pw0[4]; u0b.w[1] = pw0[5]; u0b.w[2] = pw0[6]; u0b.w[3] = pw0[7];
            u1a.w[0] = pw1[0]; u1a.w[1] = pw1[1]; u1a.w[2] = pw1[2]; u1a.w[3] = pw1[3];
            u1b.w[0] = pw1[4]; u1b.w[1] = pw1[5]; u1b.w[2] = pw1[6]; u1b.w[3] = pw1[7];
            bf16x8 pf0a = as_bf16(u0a.v), pf0b = as_bf16(u0b.v);
            bf16x8 pf1a = as_bf16(u1a.v), pf1b = as_bf16(u1b.v);
            __builtin_amdgcn_s_setprio(1);
            {
                const int drow0 = l31, dsw0 = (drow0 & 7) << 3;
                const int drow1 = 32 + l31, dsw1 = (drow1 & 7) << 3;
                const int c0 = (sub * 4 + hi) << 3;
                const int c1 = ((sub * 2 + 1) * 2 + hi) << 3;
                bf16x8 vf;
                vf = as_bf16(*(const u16x8*)&vb[drow0 * 64 + (c0 ^ dsw0)]);
                oacc00 = __builtin_amdgcn_mfma_f32_32x32x16_bf16(vf, pf0a, oacc00, 0, 0, 0);
                oacc10 = __builtin_amdgcn_mfma_f32_32x32x16_bf16(vf, pf1a, oacc10, 0, 0, 0);
                vf = as_bf16(*(const u16x8*)&vb[drow0 * 64 + (c1 ^ dsw0)]);
                oacc00 = __builtin_amdgcn_mfma_f32_32x32x16_bf16(vf, pf0b, oacc00, 0, 0, 0);
                oacc10 = __builtin_amdgcn_mfma_f32_32x32x16_bf16(vf, pf1b, oacc10, 0, 0, 0);
                vf = as_bf16(*(const u16x8*)&vb[drow1 * 64 + (c0 ^ dsw1)]);
                oacc01 = __builtin_amdgcn_mfma_f32_32x32x16_bf16(vf, pf0a, oacc01, 0, 0, 0);
                oacc11 = __builtin_amdgcn_mfma_f32_32x32x16_bf16(vf, pf1a, oacc11, 0, 0, 0);
                vf = as_bf16(*(const u16x8*)&vb[drow1 * 64 + (c1 ^ dsw1)]);
                oacc01 = __builtin_amdgcn_mfma_f32_32x32x16_bf16(vf, pf0b, oacc01, 0, 0, 0);
                oacc11 = __builtin_amdgcn_mfma_f32_32x32x16_bf16(vf, pf1b, oacc11, 0, 0, 0);
            }
            __builtin_amdgcn_s_setprio(0);
        }
    };

    STAGE(0, 0);
    STAGE(1, 1);
    for (int t = 0; t < 16; ++t) {
        if (t < 15) {
            asm volatile("s_waitcnt vmcnt(4)" ::: "memory");
        } else {
            asm volatile("s_waitcnt vmcnt(0)" ::: "memory");
        }
        __builtin_amdgcn_s_barrier();
        if (t + 2 < 16) STAGE(t + 2, (t + 2) % 3);
        tile(t, t % 3);
    }

    // ---- combine kv-groups through LDS ----
    float l0 = l_run0 + __shfl_xor(l_run0, 32);
    float l1 = l_run1 + __shfl_xor(l_run1, 32);
    __syncthreads();
    float* Oex = (float*)smem;                  // [4 ws][64 d][64 q]
    float* lsum = (float*)(smem + 65536);       // [4 ws][64 q]
    if (g == 1) {
#pragma unroll
        for (int rg = 0; rg < 4; ++rg)
#pragma unroll
            for (int rr = 0; rr < 4; ++rr) {
                int dA = hi4 + 8 * rg + rr;
                int dB = 32 + hi4 + 8 * rg + rr;
                Oex[ws * 4096 + dA * 64 + l31]      = oacc00[rg * 4 + rr];
                Oex[ws * 4096 + dB * 64 + l31]      = oacc01[rg * 4 + rr];
                Oex[ws * 4096 + dA * 64 + 32 + l31] = oacc10[rg * 4 + rr];
                Oex[ws * 4096 + dB * 64 + 32 + l31] = oacc11[rg * 4 + rr];
            }
        if (lane < 32) { lsum[ws * 64 + l31] = l0; lsum[ws * 64 + 32 + l31] = l1; }
    }
    __syncthreads();
    if (g == 0) {
        float inv0 = 1.0f / (l0 + lsum[ws * 64 + l31]);
        float inv1 = 1.0f / (l1 + lsum[ws * 64 + 32 + l31]);
        u16* cp0 = ctx + ((size_t)b * S_LEN + qr0 + l31) * HDIM + h * HD;
        u16* cp1 = ctx + ((size_t)b * S_LEN + qr0 + 32 + l31) * HDIM + h * HD;
#pragma unroll
        for (int rg = 0; rg < 4; ++rg) {
            u16x4 oA0, oB0, oA1, oB1;
#pragma unroll
            for (int rr = 0; rr < 4; ++rr) {
                int dA = hi4 + 8 * rg + rr;
                int dB = 32 + hi4 + 8 * rg + rr;
                oA0[rr] = f2bf((oacc00[rg * 4 + rr] + Oex[ws * 4096 + dA * 64 + l31]) * inv0);
                oB0[rr] = f2bf((oacc01[rg * 4 + rr] + Oex[ws * 4096 + dB * 64 + l31]) * inv0);
                oA1[rr] = f2bf((oacc10[rg * 4 + rr] + Oex[ws * 4096 + dA * 64 + 32 + l31]) * inv1);
                oB1[rr] = f2bf((oacc11[rg * 4 + rr] + Oex[ws * 4096 + dB * 64 + 32 + l31]) * inv1);
            }
            *(u16x4*)(cp0 + hi4 + 8 * rg) = oA0;
            *(u16x4*)(cp0 + 32 + hi4 + 8 * rg) = oB0;
            *(u16x4*)(cp1 + hi4 + 8 * rg) = oA1;
            *(u16x4*)(cp1 + 32 + hi4 + 8 * rg) = oB1;
        }
    }
}

// ---------------- residual + layernorm (proj in bf16) ----------------
__global__ __launch_bounds__(256) void resid_ln(const float* __restrict__ hs, const u16* __restrict__ proj,
                                                const float* __restrict__ g, const float* __restrict__ be,
                                                float* __restrict__ out) {
    int row = blockIdx.x, tid = threadIdx.x;
    int base = row * HDIM + tid * 4;
    f32x4 a = *(const f32x4*)(hs + base);
    u16x4 pb = *(const u16x4*)(proj + base);
    f32x4 x;
#pragma unroll
    for (int j = 0; j < 4; j++) x[j] = a[j] + bf2f(pb[j]);
    float s = x[0] + x[1] + x[2] + x[3];
    float sq = x[0] * x[0] + x[1] * x[1] + x[2] * x[2] + x[3] * x[3];
#pragma unroll
    for (int m = 1; m < 64; m <<= 1) {
        s += __shfl_xor(s, m);
        sq += __shfl_xor(sq, m);
    }
    __shared__ float red[8];
    int wave = tid >> 6, lane = tid & 63;
    if (lane == 0) { red[wave] = s; red[4 + wave] = sq; }
    __syncthreads();
    s = red[0] + red[1] + red[2] + red[3];
    sq = red[4] + red[5] + red[6] + red[7];
    float mean = s * (1.0f / 1024.0f);
    float var = sq * (1.0f / 1024.0f) - mean * mean;
    float rstd = rsqrtf(fmaxf(var, 0.f) + 1e-12f);
    f32x4 gg = *(const f32x4*)(g + tid * 4);
    f32x4 bb = *(const f32x4*)(be + tid * 4);
    f32x4 o;
#pragma unroll
    for (int j = 0; j < 4; j++) o[j] = (x[j] - mean) * rstd * gg[j] + bb[j];
    *(f32x4*)(out + base) = o;
}

extern "C" void kernel_launch(void* const* d_in, const int* in_sizes, int n_in,
                              void* d_out, int out_size, void* d_ws, size_t ws_size,
                              hipStream_t stream) {
    const float* hs    = (const float*)d_in[0];
    const float* amask = (const float*)d_in[1];
    const float* Wq    = (const float*)d_in[2];
    const float* bq    = (const float*)d_in[3];
    const float* Wk    = (const float*)d_in[4];
    const float* bk    = (const float*)d_in[5];
    const float* Wv    = (const float*)d_in[6];
    const float* bv    = (const float*)d_in[7];
    const float* Wd    = (const float*)d_in[8];
    const float* bd    = (const float*)d_in[9];
    const float* gamma = (const float*)d_in[10];
    const float* beta  = (const float*)d_in[11];

    char* ws = (char*)d_ws;
    u16*   hsb   = (u16*)(ws);                       // 8 MB
    u16*   Wqkvb = (u16*)(ws + ((size_t)8 << 20));   // 6 MB
    u16*   Wdb   = (u16*)(ws + ((size_t)14 << 20));  // 2 MB
    u16*   qkv   = (u16*)(ws + ((size_t)16 << 20));  // q,k planes; plane 2 = V^T
    u16*   vt    = qkv + 2 * (size_t)QKV_STRIDE;
    u16*   ctx   = (u16*)(ws + ((size_t)40 << 20));  // 8 MB
    u16*   projb = (u16*)(ws + ((size_t)48 << 20));  // 8 MB bf16
    float* b3    = (float*)(ws + ((size_t)64 << 20));// 12 KB

    prep<<<4108, 256, 0, stream>>>(hs, Wq, Wk, Wv, Wd, bq, bk, bv, hsb, Wqkvb, Wdb, b3);

    // QKV projection: [4096,1024] x [3072,1024]^T, 768 balanced blocks
    gemm_qkv<<<dim3(24, 32), 256, 0, stream>>>(hsb, Wqkvb, b3, qkv, vt);

    // attention
    flash_attn10<<<256, 512, 0, stream>>>(qkv, vt, amask, ctx);

    // output projection -> bf16
    gemm_proj<<<dim3(8, 32), 256, 0, stream>>>(ctx, Wdb, bd, projb, HDIM, HDIM);

    // residual + layernorm
    resid_ln<<<MTOK, 256, 0, stream>>>(hs, projb, gamma, beta, (float*)d_out);
}